// Round 12
// baseline (1222.973 us; speedup 1.0000x reference)
//
// Round 12: identical resubmission (7th timeout; counted-vmcnt kernel still
// never executed). Audits closed: vmcnt ledger (all 20 iters + tail), dbuf
// WAR/RAW >=2-barrier separation, rule-#18 fences after every wait (incl.
// cvt8's exposure), gl_x2 earlyclobber, WAR-on-reg for xb re-issue (SSA
// liveness + in-order VALU-read-before-VMEM-issue). Prediction: 200-260us,
// hbm 4.0-5.2 TB/s, MfmaUtil 22-30%; fallback paths pre-committed.
#include <hip/hip_runtime.h>
#include <hip/hip_bf16.h>

#define E_EDGES 500000
#define V_IN 128
#define E_IN 64
#define U_IN 64
#define NG 512
#define HID 256
#define CAT 384
#define BM 64
#define NCHUNK1 12       // 384/32
#define NCHUNK2 8        // 256/32
#define TILE 8192        // HID*32 bf16 (16 KB)

typedef short short8 __attribute__((ext_vector_type(8)));
typedef float f32x4 __attribute__((ext_vector_type(4)));

// ---- sync macros (rule #18: sched_barrier(0) after every asm wait/barrier) ----
#define WAITV(N)                                                    \
  do {                                                              \
    asm volatile("s_waitcnt vmcnt(" #N ")" ::: "memory");           \
    __builtin_amdgcn_sched_barrier(0);                              \
  } while (0)
#define WAITLGKM0                                                   \
  do {                                                              \
    asm volatile("s_waitcnt lgkmcnt(0)" ::: "memory");              \
    __builtin_amdgcn_sched_barrier(0);                              \
  } while (0)
#define BARR                                                        \
  do {                                                              \
    __builtin_amdgcn_s_barrier();                                   \
    __builtin_amdgcn_sched_barrier(0);                              \
  } while (0)

static __device__ __forceinline__ short f2bf(float f) {  // RNE (prep only)
  unsigned u = __builtin_bit_cast(unsigned, f);
  u += 0x7fffu + ((u >> 16) & 1u);
  return (short)(u >> 16);
}

static __device__ __forceinline__ void gload_lds16(const void* g, void* l) {
  __builtin_amdgcn_global_load_lds(
      (const __attribute__((address_space(1))) unsigned int*)g,
      (unsigned int __attribute__((address_space(3)))*)l, 16, 0, 0);
}

// 16 KB W tile: 4 waves x 4 x gload_lds16 = 4 vm ops per wave (deterministic).
static __device__ __forceinline__ void stage_w(const short* gsrc, short* lbase,
                                               int w, int l) {
#pragma unroll
  for (int i = 0; i < 4; ++i) {
    int off = (w * 4 + i) * 1024;
    gload_lds16((const char*)gsrc + off + l * 16, (char*)lbase + off);
  }
}

// two 16B loads, one asm block = exactly 2 vm ops; "=&v" EARLYCLOBBER so the
// async dests can never alias the address reg (WAR-on-return hazard).
static __device__ __forceinline__ void gl_x2(uint64_t addr, f32x4& d0, f32x4& d1) {
  asm volatile(
      "global_load_dwordx4 %0, %2, off\n\t"
      "global_load_dwordx4 %1, %2, off offset:16"
      : "=&v"(d0), "=&v"(d1)
      : "v"(addr)
      : "memory");
}

// 8 f32 -> short8 bf16 via HW RNE pack
static __device__ __forceinline__ short8 cvt8(f32x4 a, f32x4 b) {
  union { unsigned u[4]; short8 s; } r;
  asm("v_cvt_pk_bf16_f32 %0, %1, %2" : "=v"(r.u[0]) : "v"(a[0]), "v"(a[1]));
  asm("v_cvt_pk_bf16_f32 %0, %1, %2" : "=v"(r.u[1]) : "v"(a[2]), "v"(a[3]));
  asm("v_cvt_pk_bf16_f32 %0, %1, %2" : "=v"(r.u[2]) : "v"(b[0]), "v"(b[1]));
  asm("v_cvt_pk_bf16_f32 %0, %1, %2" : "=v"(r.u[3]) : "v"(b[2]), "v"(b[3]));
  return r.s;
}

// W1/W2 -> bf16 [n][k]-tiles, k-block XOR swizzle (unchanged)
__global__ void prep_weights(const float* __restrict__ W1,
                             const float* __restrict__ W2,
                             short* __restrict__ w1t, short* __restrict__ w2t) {
  int idx = blockIdx.x * 256 + threadIdx.x;
  if (idx < CAT * HID) {
    int kc = idx >> 13;
    int rem = idx & (TILE - 1);
    int n = rem >> 5, kk = rem & 31;
    int swz = ((((kk >> 3) ^ (n & 3)) << 3) | (kk & 7));
    w1t[kc * TILE + n * 32 + swz] = f2bf(W1[(size_t)(kc * 32 + kk) * HID + n]);
  } else if (idx < CAT * HID + HID * HID) {
    int j = idx - CAT * HID;
    int kc = j >> 13;
    int rem = j & (TILE - 1);
    int n = rem >> 5, kk = rem & 31;
    int swz = ((((kk >> 3) ^ (n & 3)) << 3) | (kk & 7));
    w2t[kc * TILE + n * 32 + swz] = f2bf(W2[(size_t)(kc * 32 + kk) * HID + n]);
  }
}

__global__ __launch_bounds__(256, 2) void edge_mlp(
    const float* __restrict__ src, const float* __restrict__ dst,
    const float* __restrict__ edg, const float* __restrict__ u,
    const int* __restrict__ batch,
    const float* __restrict__ b1, const float* __restrict__ b2,
    const short* __restrict__ w1t, const short* __restrict__ w2t,
    float* __restrict__ out) {
  // LDS: 32768 + 33792 + 2048 = 68608 B -> 2 blocks/CU
  __shared__ short wsl[2][TILE];
  __shared__ short hs[BM][264];
  __shared__ float biasLds[2 * HID];

  const int t = threadIdx.x;
  const int l = t & 63;
  const int wc = t >> 6;
  const int l15 = l & 15, lg = l >> 4;
  const int r0 = blockIdx.x * BM;

  // ---- prologue (all vm/lgkm here retire before/at chunk-0's wait) ----
  biasLds[t] = b1[t];
  biasLds[t + HID] = b2[t];

  uint64_t rowkSD[4], rowkE[4], rowkU[4];
#pragma unroll
  for (int m = 0; m < 4; ++m) {
    int gr = r0 + m * 16 + l15;
    if (gr >= E_EDGES) gr = E_EDGES - 1;        // tail clamp (stores guarded)
    int bi = batch[gr];
    bi = bi < 0 ? 0 : (bi >= NG ? NG - 1 : bi);
    rowkSD[m] = (uint64_t)gr * 512u + (unsigned)(lg * 32);
    rowkE[m]  = (uint64_t)gr * 256u + (unsigned)(lg * 32);
    rowkU[m]  = (uint64_t)(const char*)u + (uint64_t)bi * 256u + (unsigned)(lg * 32);
  }
  const uint64_t sbase = (uint64_t)(const char*)src;
  const uint64_t dbase = (uint64_t)(const char*)dst;
  const uint64_t ebase = (uint64_t)(const char*)edg;

  WAITLGKM0;       // bias ds_writes drained (visibility at epilogue-1)
  BARR;

  f32x4 xb[2][4][2];

  // chunk kc -> per-m global byte address (kc constant after unroll)
#define XADDR(kc_, m_)                                                       \
  ((kc_) < 4    ? sbase + rowkSD[m_] + (uint64_t)((kc_)*128)                 \
   : (kc_) < 8  ? dbase + rowkSD[m_] + (uint64_t)(((kc_)-4) * 128)           \
   : (kc_) < 10 ? ebase + rowkE[m_] + (uint64_t)(((kc_)-8) * 128)            \
                : rowkU[m_] + (uint64_t)(((kc_)-10) * 128))

#define ISSUE_X(kc_)                                                         \
  do {                                                                       \
    _Pragma("unroll") for (int m = 0; m < 4; ++m)                            \
        gl_x2(XADDR(kc_, m), xb[(kc_)&1][m][0], xb[(kc_)&1][m][1]);          \
  } while (0)

  // queue: [W(0):4][x(0):8][x(1):8]
  stage_w(w1t, wsl[0], wc, l);
  ISSUE_X(0);
  ISSUE_X(1);

  f32x4 acc[4][4];
#pragma unroll
  for (int m = 0; m < 4; ++m)
#pragma unroll
    for (int n = 0; n < 4; ++n)
#pragma unroll
      for (int j = 0; j < 4; ++j) acc[m][n][j] = 0.f;

  // ---------------- layer 1 ----------------
  // steady queue pre-wait: [x(kc):8][W(kc):4][x(kc+1):8] -> vmcnt(8)
#pragma unroll
  for (int kc = 0; kc < NCHUNK1; ++kc) {
    if (kc < NCHUNK1 - 1) WAITV(8); else WAITV(0);
    short8 a[4];
#pragma unroll
    for (int m = 0; m < 4; ++m)
      a[m] = cvt8(xb[kc & 1][m][0], xb[kc & 1][m][1]);
    BARR;  // all waves' W(kc) shares visible; all readers left buf[(kc+1)&1]

    if (kc < NCHUNK1 - 1)
      stage_w(w1t + (kc + 1) * TILE, wsl[(kc + 1) & 1], wc, l);
    else
      stage_w(w2t, wsl[0], wc, l);   // W2(0); buf0 free (chunk 10 done)
    if (kc < NCHUNK1 - 2) ISSUE_X(kc + 2);   // overwrites xb[kc&1] (a[] cvt'd)

    const short* wcur = wsl[kc & 1];
    short8 b[4];
#pragma unroll
    for (int n = 0; n < 4; ++n) {
      int nn = wc * 64 + n * 16 + l15;
      int blk = lg ^ (nn & 3);
      b[n] = *(const short8*)&wcur[nn * 32 + blk * 8];
    }
#pragma unroll
    for (int m = 0; m < 4; ++m)
#pragma unroll
      for (int n = 0; n < 4; ++n)
        acc[m][n] = __builtin_amdgcn_mfma_f32_16x16x32_bf16(a[m], b[n], acc[m][n], 0, 0, 0);
    BARR;  // no wave may restage over buf[kc&1] while laggards read it
  }

  // epilogue 1: bias+relu+cvt -> hs
#pragma unroll
  for (int n = 0; n < 4; ++n) {
    int col = wc * 64 + n * 16 + l15;
    float bv = biasLds[col];
#pragma unroll
    for (int m = 0; m < 4; ++m)
#pragma unroll
      for (int j = 0; j < 4; ++j) {
        int row = m * 16 + lg * 4 + j;
        hs[row][col] = f2bf(fmaxf(acc[m][n][j] + bv, 0.f));
      }
  }
#pragma unroll
  for (int m = 0; m < 4; ++m)
#pragma unroll
    for (int n = 0; n < 4; ++n)
#pragma unroll
      for (int j = 0; j < 4; ++j) acc[m][n][j] = 0.f;

  WAITLGKM0;   // hs writes drained before cross-wave read
  BARR;

  // ---------------- layer 2 ----------------
  // queue pre-wait: [W2(kc):4] -> vmcnt(0) (L2-fed, 1 chunk in flight)
#pragma unroll
  for (int kc = 0; kc < NCHUNK2; ++kc) {
    WAITV(0);
    BARR;
    if (kc < NCHUNK2 - 1)
      stage_w(w2t + (kc + 1) * TILE, wsl[(kc + 1) & 1], wc, l);

    const short* wcur = wsl[kc & 1];
    short8 a[4], b[4];
#pragma unroll
    for (int m = 0; m < 4; ++m)
      a[m] = *(const short8*)&hs[m * 16 + l15][kc * 32 + lg * 8];
#pragma unroll
    for (int n = 0; n < 4; ++n) {
      int nn = wc * 64 + n * 16 + l15;
      int blk = lg ^ (nn & 3);
      b[n] = *(const short8*)&wcur[nn * 32 + blk * 8];
    }
#pragma unroll
    for (int m = 0; m < 4; ++m)
#pragma unroll
      for (int n = 0; n < 4; ++n)
        acc[m][n] = __builtin_amdgcn_mfma_f32_16x16x32_bf16(a[m], b[n], acc[m][n], 0, 0, 0);
    BARR;
  }

  // epilogue 2: bias + guarded stores
#pragma unroll
  for (int n = 0; n < 4; ++n) {
    int col = wc * 64 + n * 16 + l15;
    float bv = biasLds[HID + col];
#pragma unroll
    for (int m = 0; m < 4; ++m) {
      int rbase = r0 + m * 16 + lg * 4;
#pragma unroll
      for (int j = 0; j < 4; ++j) {
        int r = rbase + j;
        if (r < E_EDGES) out[(size_t)r * HID + col] = acc[m][n][j] + bv;
      }
    }
  }
}

extern "C" void kernel_launch(void* const* d_in, const int* in_sizes, int n_in,
                              void* d_out, int out_size, void* d_ws, size_t ws_size,
                              hipStream_t stream) {
  const float* src = (const float*)d_in[0];
  const float* dst = (const float*)d_in[1];
  const float* edg = (const float*)d_in[2];
  const float* u   = (const float*)d_in[3];
  const int* batch = (const int*)d_in[4];
  const float* W1 = (const float*)d_in[5];
  const float* b1 = (const float*)d_in[6];
  const float* W2 = (const float*)d_in[7];
  const float* b2 = (const float*)d_in[8];
  float* out = (float*)d_out;

  short* w1t = (short*)d_ws;
  short* w2t = w1t + CAT * HID;

  int prep_grid = (CAT * HID + HID * HID) / 256;  // 640
  prep_weights<<<prep_grid, 256, 0, stream>>>(W1, W2, w1t, w2t);

  int grid = (E_EDGES + BM - 1) / BM;  // 7813
  edge_mlp<<<grid, 256, 0, stream>>>(src, dst, edg, u, batch, b1, b2, w1t, w2t, out);
}